// Round 1
// baseline (576.107 us; speedup 1.0000x reference)
//
#include <hip/hip_runtime.h>
#include <math.h>

#define D 128
#define D4 32   // D/4 float4s per row

// ---------------- CSR build ----------------

__global__ void count_kernel(const int* __restrict__ dst, int* __restrict__ counts, int E) {
    int e = blockIdx.x * 256 + threadIdx.x;
    if (e < E) atomicAdd(&counts[dst[e]], 1);
}

// per-256-chunk sums of counts; also dis[i] = rsqrt(deg) with deg = indeg+1 (self loop)
__global__ void block_sum_kernel(const int* __restrict__ counts, float* __restrict__ dis,
                                 int* __restrict__ bsums, int N) {
    __shared__ int sh[256];
    int t = threadIdx.x;
    int i = blockIdx.x * 256 + t;
    int v = (i < N) ? counts[i] : 0;
    if (i < N) dis[i] = rsqrtf((float)v + 1.0f);
    sh[t] = v;
    __syncthreads();
    for (int off = 128; off > 0; off >>= 1) {
        if (t < off) sh[t] += sh[t + off];
        __syncthreads();
    }
    if (t == 0) bsums[blockIdx.x] = sh[0];
}

// exclusive scan of NB (<=256) block sums, in place
__global__ void scan_bsums_kernel(int* __restrict__ bsums, int NB) {
    __shared__ int sh[256];
    int t = threadIdx.x;
    int v = (t < NB) ? bsums[t] : 0;
    sh[t] = v;
    __syncthreads();
    for (int off = 1; off < 256; off <<= 1) {
        int x = (t >= off) ? sh[t - off] : 0;
        __syncthreads();
        sh[t] += x;
        __syncthreads();
    }
    if (t < NB) bsums[t] = sh[t] - v;  // exclusive
}

__global__ void scan_scatter_kernel(const int* __restrict__ counts, const int* __restrict__ bsums,
                                    int* __restrict__ row_ptr, int N, int E) {
    __shared__ int sh[256];
    int t = threadIdx.x;
    int i = blockIdx.x * 256 + t;
    int v = (i < N) ? counts[i] : 0;
    sh[t] = v;
    __syncthreads();
    for (int off = 1; off < 256; off <<= 1) {
        int x = (t >= off) ? sh[t - off] : 0;
        __syncthreads();
        sh[t] += x;
        __syncthreads();
    }
    if (i < N) row_ptr[i] = bsums[blockIdx.x] + sh[t] - v;
    if (i == 0) row_ptr[N] = E;
}

__global__ void fill_csr_kernel(const int* __restrict__ src, const int* __restrict__ dst,
                                const int* __restrict__ row_ptr, int* __restrict__ fill,
                                int* __restrict__ col, int E) {
    int e = blockIdx.x * 256 + threadIdx.x;
    if (e < E) {
        int d = dst[e];
        int pos = atomicAdd(&fill[d], 1);
        col[row_ptr[d] + pos] = src[e];
    }
}

// ---------------- GEMM: C[N x 128] = A[N x 128] @ W[128 x 128] (fp32) ----------------
// 32 rows per block, 256 threads = 8 row-groups x 32 col-groups, 4x4 register blocking.
// W staged in two 64-row k-chunks (32KB) + X tile (16KB) => 48KB LDS, 3 blocks/CU.

__global__ __launch_bounds__(256) void gemm_kernel(const float* __restrict__ A,
                                                   const float* __restrict__ W,
                                                   float* __restrict__ C, int N) {
    __shared__ float Wl[64 * D];   // 32KB: 64 k-rows of W
    __shared__ float4 Xs[32 * D4]; // 16KB: 32 rows x 128 floats

    int t = threadIdx.x;
    int row0 = blockIdx.x * 32;
    const float4* A4 = (const float4*)A;
    for (int i = t; i < 32 * D4; i += 256) {
        int r = row0 + (i >> 5);
        Xs[i] = (r < N) ? A4[(size_t)r * D4 + (i & 31)] : make_float4(0.f, 0.f, 0.f, 0.f);
    }

    int cg = t & 31;   // 4-col group: cols 4*cg..4*cg+3
    int rg = t >> 5;   // row group: local rows rg*4..rg*4+3
    float4 acc[4];
#pragma unroll
    for (int rr = 0; rr < 4; rr++) acc[rr] = make_float4(0.f, 0.f, 0.f, 0.f);

    const float4* W4 = (const float4*)W;
    float4* Wl4w = (float4*)Wl;
    const float4* Wl4 = (const float4*)Wl;

    for (int p = 0; p < 2; p++) {
        __syncthreads();  // protect Wl readers from previous phase / Xs staging
        // stage k rows [p*64, p*64+64) of W: 64*128 floats = 2048 float4
        for (int i = t; i < 2048; i += 256) Wl4w[i] = W4[p * 2048 + i];
        __syncthreads();
#pragma unroll 4
        for (int k4 = 0; k4 < 16; k4++) {   // local k = k4*4 .. k4*4+3
            float4 w0 = Wl4[(k4 * 4 + 0) * D4 + cg];
            float4 w1 = Wl4[(k4 * 4 + 1) * D4 + cg];
            float4 w2 = Wl4[(k4 * 4 + 2) * D4 + cg];
            float4 w3 = Wl4[(k4 * 4 + 3) * D4 + cg];
            int kg = p * 16 + k4;  // global k4 index into Xs
#pragma unroll
            for (int rr = 0; rr < 4; rr++) {
                float4 xv = Xs[(rg * 4 + rr) * D4 + kg];
                acc[rr].x = fmaf(xv.x, w0.x, fmaf(xv.y, w1.x, fmaf(xv.z, w2.x, fmaf(xv.w, w3.x, acc[rr].x))));
                acc[rr].y = fmaf(xv.x, w0.y, fmaf(xv.y, w1.y, fmaf(xv.z, w2.y, fmaf(xv.w, w3.y, acc[rr].y))));
                acc[rr].z = fmaf(xv.x, w0.z, fmaf(xv.y, w1.z, fmaf(xv.z, w2.z, fmaf(xv.w, w3.z, acc[rr].z))));
                acc[rr].w = fmaf(xv.x, w0.w, fmaf(xv.y, w1.w, fmaf(xv.z, w2.w, fmaf(xv.w, w3.w, acc[rr].w))));
            }
        }
    }

    float4* C4 = (float4*)C;
#pragma unroll
    for (int rr = 0; rr < 4; rr++) {
        int r = row0 + rg * 4 + rr;
        if (r < N) C4[(size_t)r * D4 + cg] = acc[rr];
    }
}

// ---------------- Aggregation: out[i] = relu(b + dis_i*(sum_s dis_s*h[s] + dis_i*h[i])) --------
// 32 lanes per node (float4 over feature dim), 8 nodes per 256-block, pull-mode (no atomics).

__global__ void agg_kernel(const float* __restrict__ h, const float* __restrict__ bias,
                           const int* __restrict__ row_ptr, const int* __restrict__ col,
                           const float* __restrict__ dis, float* __restrict__ out, int N) {
    int t = threadIdx.x;
    int node = blockIdx.x * 8 + (t >> 5);
    int lane = t & 31;
    if (node >= N) return;

    const float4* h4 = (const float4*)h;
    float di = dis[node];
    float4 hv = h4[(size_t)node * D4 + lane];
    float4 acc;
    acc.x = di * hv.x; acc.y = di * hv.y; acc.z = di * hv.z; acc.w = di * hv.w;

    int e0 = row_ptr[node], e1 = row_ptr[node + 1];
    for (int e = e0; e < e1; e++) {
        int s = col[e];
        float ds = dis[s];
        float4 sv = h4[(size_t)s * D4 + lane];
        acc.x = fmaf(ds, sv.x, acc.x);
        acc.y = fmaf(ds, sv.y, acc.y);
        acc.z = fmaf(ds, sv.z, acc.z);
        acc.w = fmaf(ds, sv.w, acc.w);
    }

    const float4* b4 = (const float4*)bias;
    float4 bb = b4[lane];
    float4 o;
    o.x = fmaxf(fmaf(di, acc.x, bb.x), 0.f);
    o.y = fmaxf(fmaf(di, acc.y, bb.y), 0.f);
    o.z = fmaxf(fmaf(di, acc.z, bb.z), 0.f);
    o.w = fmaxf(fmaf(di, acc.w, bb.w), 0.f);
    ((float4*)out)[(size_t)node * D4 + lane] = o;
}

// ---------------- Head: scores[i] = sigmoid(dot(x[i], head_w) + head_b) ----------------

__global__ void head_kernel(const float* __restrict__ x, const float* __restrict__ hw,
                            const float* __restrict__ hb, float* __restrict__ out, int N) {
    int t = threadIdx.x;
    int node = blockIdx.x * 8 + (t >> 5);
    int lane = t & 31;
    const float4* x4 = (const float4*)x;
    const float4* w4 = (const float4*)hw;
    float s = 0.f;
    if (node < N) {
        float4 xv = x4[(size_t)node * D4 + lane];
        float4 wv = w4[lane];
        s = xv.x * wv.x + xv.y * wv.y + xv.z * wv.z + xv.w * wv.w;
    }
    // reduce across the 32-lane node group (xor masks 1..16 stay within the group)
    for (int m = 1; m < 32; m <<= 1) s += __shfl_xor(s, m, 64);
    if (node < N && lane == 0) {
        float v = s + hb[0];
        out[node] = 1.0f / (1.0f + expf(-v));
    }
}

// ---------------- launch ----------------

extern "C" void kernel_launch(void* const* d_in, const int* in_sizes, int n_in,
                              void* d_out, int out_size, void* d_ws, size_t ws_size,
                              hipStream_t stream) {
    const int*   edge   = (const int*)d_in[0];
    const float* emb    = (const float*)d_in[1];
    const float* W1     = (const float*)d_in[2];
    const float* b1     = (const float*)d_in[3];
    const float* W2     = (const float*)d_in[4];
    const float* b2     = (const float*)d_in[5];
    const float* head_w = (const float*)d_in[6];
    const float* head_b = (const float*)d_in[7];
    float* out = (float*)d_out;

    int E = in_sizes[0] / 2;
    int N = in_sizes[1] / D;
    const int* srcp = edge;
    const int* dstp = edge + E;

    // workspace carve-up (16B aligned)
    char* w = (char*)d_ws;
    auto alloc = [&](size_t bytes) -> char* {
        char* p = w;
        w += (bytes + 15) & ~(size_t)15;
        return p;
    };
    float* bufA    = (float*)alloc((size_t)N * D * 4);   // 25.6 MB
    float* bufB    = (float*)alloc((size_t)N * D * 4);   // 25.6 MB
    int*   col     = (int*)  alloc((size_t)E * 4);       // 6.4 MB
    int*   counts  = (int*)  alloc((size_t)N * 4);
    int*   fill    = (int*)  alloc((size_t)N * 4);
    int*   row_ptr = (int*)  alloc((size_t)(N + 1) * 4);
    float* dis     = (float*)alloc((size_t)N * 4);
    int*   bsums   = (int*)  alloc(1024);

    int NB = (N + 255) / 256;       // 196 (<=256 required by scan_bsums)
    int gE = (E + 255) / 256;       // 6250
    int gG = (N + 31) / 32;         // 1563
    int gA = (N + 7) / 8;           // 6250

    hipMemsetAsync(counts, 0, (size_t)N * 4, stream);
    hipMemsetAsync(fill,   0, (size_t)N * 4, stream);

    count_kernel<<<gE, 256, 0, stream>>>(dstp, counts, E);
    block_sum_kernel<<<NB, 256, 0, stream>>>(counts, dis, bsums, N);
    scan_bsums_kernel<<<1, 256, 0, stream>>>(bsums, NB);
    scan_scatter_kernel<<<NB, 256, 0, stream>>>(counts, bsums, row_ptr, N, E);
    fill_csr_kernel<<<gE, 256, 0, stream>>>(srcp, dstp, row_ptr, fill, col, E);

    gemm_kernel<<<gG, 256, 0, stream>>>(emb, W1, bufA, N);            // h1 = emb @ W1
    agg_kernel<<<gA, 256, 0, stream>>>(bufA, b1, row_ptr, col, dis, bufB, N);  // x1
    gemm_kernel<<<gG, 256, 0, stream>>>(bufB, W2, bufA, N);           // h2 = x1 @ W2
    agg_kernel<<<gA, 256, 0, stream>>>(bufA, b2, row_ptr, col, dis, bufB, N);  // x2
    head_kernel<<<gA, 256, 0, stream>>>(bufB, head_w, head_b, out, N);
}

// Round 2
// 524.042 us; speedup vs baseline: 1.0994x; 1.0994x over previous
//
#include <hip/hip_runtime.h>
#include <math.h>

#define D 128
#define D4 32   // D/4 float4s per row

// ---------------- CSR build ----------------

__global__ void count_kernel(const int* __restrict__ dst, int* __restrict__ counts, int E) {
    int e = blockIdx.x * 256 + threadIdx.x;
    if (e < E) atomicAdd(&counts[dst[e]], 1);
}

// per-256-chunk sums of counts; also dis[i] = rsqrt(deg) with deg = indeg+1 (self loop)
__global__ void block_sum_kernel(const int* __restrict__ counts, float* __restrict__ dis,
                                 int* __restrict__ bsums, int N) {
    __shared__ int sh[256];
    int t = threadIdx.x;
    int i = blockIdx.x * 256 + t;
    int v = (i < N) ? counts[i] : 0;
    if (i < N) dis[i] = rsqrtf((float)v + 1.0f);
    sh[t] = v;
    __syncthreads();
    for (int off = 128; off > 0; off >>= 1) {
        if (t < off) sh[t] += sh[t + off];
        __syncthreads();
    }
    if (t == 0) bsums[blockIdx.x] = sh[0];
}

// exclusive scan of NB (<=256) block sums, in place
__global__ void scan_bsums_kernel(int* __restrict__ bsums, int NB) {
    __shared__ int sh[256];
    int t = threadIdx.x;
    int v = (t < NB) ? bsums[t] : 0;
    sh[t] = v;
    __syncthreads();
    for (int off = 1; off < 256; off <<= 1) {
        int x = (t >= off) ? sh[t - off] : 0;
        __syncthreads();
        sh[t] += x;
        __syncthreads();
    }
    if (t < NB) bsums[t] = sh[t] - v;  // exclusive
}

__global__ void scan_scatter_kernel(const int* __restrict__ counts, const int* __restrict__ bsums,
                                    int* __restrict__ row_ptr, int N, int E) {
    __shared__ int sh[256];
    int t = threadIdx.x;
    int i = blockIdx.x * 256 + t;
    int v = (i < N) ? counts[i] : 0;
    sh[t] = v;
    __syncthreads();
    for (int off = 1; off < 256; off <<= 1) {
        int x = (t >= off) ? sh[t - off] : 0;
        __syncthreads();
        sh[t] += x;
        __syncthreads();
    }
    if (i < N) row_ptr[i] = bsums[blockIdx.x] + sh[t] - v;
    if (i == 0) row_ptr[N] = E;
}

__global__ void fill_csr_kernel(const int* __restrict__ src, const int* __restrict__ dst,
                                const int* __restrict__ row_ptr, int* __restrict__ fill,
                                int* __restrict__ col, int E) {
    int e = blockIdx.x * 256 + threadIdx.x;
    if (e < E) {
        int d = dst[e];
        int pos = atomicAdd(&fill[d], 1);
        col[row_ptr[d] + pos] = src[e];
    }
}

// ---------------- GEMM: C[N x 128] = dis[row] * (A[N x 128] @ W[128 x 128]) (fp32) ----
// 32 rows per block, 256 threads = 8 row-groups x 32 col-groups, 4x4 register blocking.
// Epilogue pre-scales each output row by dis[row] so aggregation is a pure gather-sum.

__global__ __launch_bounds__(256) void gemm_kernel(const float* __restrict__ A,
                                                   const float* __restrict__ W,
                                                   const float* __restrict__ dis,
                                                   float* __restrict__ C, int N) {
    __shared__ float Wl[64 * D];   // 32KB: 64 k-rows of W
    __shared__ float4 Xs[32 * D4]; // 16KB: 32 rows x 128 floats

    int t = threadIdx.x;
    int row0 = blockIdx.x * 32;
    const float4* A4 = (const float4*)A;
    for (int i = t; i < 32 * D4; i += 256) {
        int r = row0 + (i >> 5);
        Xs[i] = (r < N) ? A4[(size_t)r * D4 + (i & 31)] : make_float4(0.f, 0.f, 0.f, 0.f);
    }

    int cg = t & 31;   // 4-col group: cols 4*cg..4*cg+3
    int rg = t >> 5;   // row group: local rows rg*4..rg*4+3
    float4 acc[4];
#pragma unroll
    for (int rr = 0; rr < 4; rr++) acc[rr] = make_float4(0.f, 0.f, 0.f, 0.f);

    const float4* W4 = (const float4*)W;
    float4* Wl4w = (float4*)Wl;
    const float4* Wl4 = (const float4*)Wl;

    for (int p = 0; p < 2; p++) {
        __syncthreads();  // protect Wl readers from previous phase / Xs staging
        for (int i = t; i < 2048; i += 256) Wl4w[i] = W4[p * 2048 + i];
        __syncthreads();
#pragma unroll 4
        for (int k4 = 0; k4 < 16; k4++) {   // local k = k4*4 .. k4*4+3
            float4 w0 = Wl4[(k4 * 4 + 0) * D4 + cg];
            float4 w1 = Wl4[(k4 * 4 + 1) * D4 + cg];
            float4 w2 = Wl4[(k4 * 4 + 2) * D4 + cg];
            float4 w3 = Wl4[(k4 * 4 + 3) * D4 + cg];
            int kg = p * 16 + k4;
#pragma unroll
            for (int rr = 0; rr < 4; rr++) {
                float4 xv = Xs[(rg * 4 + rr) * D4 + kg];
                acc[rr].x = fmaf(xv.x, w0.x, fmaf(xv.y, w1.x, fmaf(xv.z, w2.x, fmaf(xv.w, w3.x, acc[rr].x))));
                acc[rr].y = fmaf(xv.x, w0.y, fmaf(xv.y, w1.y, fmaf(xv.z, w2.y, fmaf(xv.w, w3.y, acc[rr].y))));
                acc[rr].z = fmaf(xv.x, w0.z, fmaf(xv.y, w1.z, fmaf(xv.z, w2.z, fmaf(xv.w, w3.z, acc[rr].z))));
                acc[rr].w = fmaf(xv.x, w0.w, fmaf(xv.y, w1.w, fmaf(xv.z, w2.w, fmaf(xv.w, w3.w, acc[rr].w))));
            }
        }
    }

    float4* C4 = (float4*)C;
#pragma unroll
    for (int rr = 0; rr < 4; rr++) {
        int r = row0 + rg * 4 + rr;
        if (r < N) {
            float dr = dis[r];
            float4 o = acc[rr];
            o.x *= dr; o.y *= dr; o.z *= dr; o.w *= dr;
            C4[(size_t)r * D4 + cg] = o;
        }
    }
}

// ---------------- Aggregation (pull, 8-way unrolled gather) ----------------
// hs is pre-scaled: hs[s] = dis[s]*h[s].  out[i] = relu(b + dis[i]*(sum_nbr hs[s] + hs[i]))
// 32 lanes per node (float4 over feature dim), 8 nodes per 256-block.

#define GATHER8(E0)                                                     \
    {                                                                   \
        int s0 = col[(E0)+0], s1 = col[(E0)+1], s2 = col[(E0)+2], s3 = col[(E0)+3]; \
        int s4 = col[(E0)+4], s5 = col[(E0)+5], s6 = col[(E0)+6], s7 = col[(E0)+7]; \
        float4 v0 = h4[(size_t)s0 * D4 + lane];                         \
        float4 v1 = h4[(size_t)s1 * D4 + lane];                         \
        float4 v2 = h4[(size_t)s2 * D4 + lane];                         \
        float4 v3 = h4[(size_t)s3 * D4 + lane];                         \
        float4 v4 = h4[(size_t)s4 * D4 + lane];                         \
        float4 v5 = h4[(size_t)s5 * D4 + lane];                         \
        float4 v6 = h4[(size_t)s6 * D4 + lane];                         \
        float4 v7 = h4[(size_t)s7 * D4 + lane];                         \
        acc.x += ((v0.x + v1.x) + (v2.x + v3.x)) + ((v4.x + v5.x) + (v6.x + v7.x)); \
        acc.y += ((v0.y + v1.y) + (v2.y + v3.y)) + ((v4.y + v5.y) + (v6.y + v7.y)); \
        acc.z += ((v0.z + v1.z) + (v2.z + v3.z)) + ((v4.z + v5.z) + (v6.z + v7.z)); \
        acc.w += ((v0.w + v1.w) + (v2.w + v3.w)) + ((v4.w + v5.w) + (v6.w + v7.w)); \
    }

__global__ void agg_kernel(const float* __restrict__ hs, const float* __restrict__ bias,
                           const int* __restrict__ row_ptr, const int* __restrict__ col,
                           const float* __restrict__ dis, float* __restrict__ out, int N) {
    int t = threadIdx.x;
    int node = blockIdx.x * 8 + (t >> 5);
    int lane = t & 31;
    if (node >= N) return;

    const float4* h4 = (const float4*)hs;
    float4 acc = h4[(size_t)node * D4 + lane];   // self term (pre-scaled)

    int e0 = row_ptr[node], e1 = row_ptr[node + 1];
    int e = e0;
    for (; e + 8 <= e1; e += 8) GATHER8(e)
    for (; e < e1; e++) {
        int s = col[e];
        float4 v = h4[(size_t)s * D4 + lane];
        acc.x += v.x; acc.y += v.y; acc.z += v.z; acc.w += v.w;
    }

    float di = dis[node];
    float4 bb = ((const float4*)bias)[lane];
    float4 o;
    o.x = fmaxf(fmaf(di, acc.x, bb.x), 0.f);
    o.y = fmaxf(fmaf(di, acc.y, bb.y), 0.f);
    o.z = fmaxf(fmaf(di, acc.z, bb.z), 0.f);
    o.w = fmaxf(fmaf(di, acc.w, bb.w), 0.f);
    ((float4*)out)[(size_t)node * D4 + lane] = o;
}

// Layer-2 aggregation with the sigmoid head fused: writes one score per node.
__global__ void agg_head_kernel(const float* __restrict__ hs, const float* __restrict__ bias,
                                const int* __restrict__ row_ptr, const int* __restrict__ col,
                                const float* __restrict__ dis,
                                const float* __restrict__ head_w, const float* __restrict__ head_b,
                                float* __restrict__ out, int N) {
    int t = threadIdx.x;
    int node = blockIdx.x * 8 + (t >> 5);
    int lane = t & 31;
    if (node >= N) return;

    const float4* h4 = (const float4*)hs;
    float4 acc = h4[(size_t)node * D4 + lane];

    int e0 = row_ptr[node], e1 = row_ptr[node + 1];
    int e = e0;
    for (; e + 8 <= e1; e += 8) GATHER8(e)
    for (; e < e1; e++) {
        int s = col[e];
        float4 v = h4[(size_t)s * D4 + lane];
        acc.x += v.x; acc.y += v.y; acc.z += v.z; acc.w += v.w;
    }

    float di = dis[node];
    float4 bb = ((const float4*)bias)[lane];
    float4 o;
    o.x = fmaxf(fmaf(di, acc.x, bb.x), 0.f);
    o.y = fmaxf(fmaf(di, acc.y, bb.y), 0.f);
    o.z = fmaxf(fmaf(di, acc.z, bb.z), 0.f);
    o.w = fmaxf(fmaf(di, acc.w, bb.w), 0.f);

    float4 wv = ((const float4*)head_w)[lane];
    float s = o.x * wv.x + o.y * wv.y + o.z * wv.z + o.w * wv.w;
    for (int m = 1; m < 32; m <<= 1) s += __shfl_xor(s, m, 64);
    if (lane == 0) {
        float v = s + head_b[0];
        out[node] = 1.0f / (1.0f + expf(-v));
    }
}

// ---------------- launch ----------------

extern "C" void kernel_launch(void* const* d_in, const int* in_sizes, int n_in,
                              void* d_out, int out_size, void* d_ws, size_t ws_size,
                              hipStream_t stream) {
    const int*   edge   = (const int*)d_in[0];
    const float* emb    = (const float*)d_in[1];
    const float* W1     = (const float*)d_in[2];
    const float* b1     = (const float*)d_in[3];
    const float* W2     = (const float*)d_in[4];
    const float* b2     = (const float*)d_in[5];
    const float* head_w = (const float*)d_in[6];
    const float* head_b = (const float*)d_in[7];
    float* out = (float*)d_out;

    int E = in_sizes[0] / 2;
    int N = in_sizes[1] / D;
    const int* srcp = edge;
    const int* dstp = edge + E;

    char* w = (char*)d_ws;
    auto alloc = [&](size_t bytes) -> char* {
        char* p = w;
        w += (bytes + 15) & ~(size_t)15;
        return p;
    };
    float* bufA    = (float*)alloc((size_t)N * D * 4);   // 25.6 MB
    float* bufB    = (float*)alloc((size_t)N * D * 4);   // 25.6 MB
    int*   col     = (int*)  alloc((size_t)E * 4);       // 6.4 MB
    int*   counts  = (int*)  alloc((size_t)N * 4);
    int*   fill    = (int*)  alloc((size_t)N * 4);
    int*   row_ptr = (int*)  alloc((size_t)(N + 1) * 4);
    float* dis     = (float*)alloc((size_t)N * 4);
    int*   bsums   = (int*)  alloc(1024);

    int NB = (N + 255) / 256;       // 196 (<=256 required by scan_bsums)
    int gE = (E + 255) / 256;       // 6250
    int gG = (N + 31) / 32;         // 1563
    int gA = (N + 7) / 8;           // 6250

    hipMemsetAsync(counts, 0, (size_t)N * 4, stream);
    hipMemsetAsync(fill,   0, (size_t)N * 4, stream);

    count_kernel<<<gE, 256, 0, stream>>>(dstp, counts, E);
    block_sum_kernel<<<NB, 256, 0, stream>>>(counts, dis, bsums, N);
    scan_bsums_kernel<<<1, 256, 0, stream>>>(bsums, NB);
    scan_scatter_kernel<<<NB, 256, 0, stream>>>(counts, bsums, row_ptr, N, E);
    fill_csr_kernel<<<gE, 256, 0, stream>>>(srcp, dstp, row_ptr, fill, col, E);

    gemm_kernel<<<gG, 256, 0, stream>>>(emb, W1, dis, bufA, N);                   // hs1
    agg_kernel<<<gA, 256, 0, stream>>>(bufA, b1, row_ptr, col, dis, bufB, N);     // x1
    gemm_kernel<<<gG, 256, 0, stream>>>(bufB, W2, dis, bufA, N);                  // hs2
    agg_head_kernel<<<gA, 256, 0, stream>>>(bufA, b2, row_ptr, col, dis,
                                            head_w, head_b, out, N);              // scores
}

// Round 3
// 411.575 us; speedup vs baseline: 1.3998x; 1.2733x over previous
//
#include <hip/hip_runtime.h>
#include <hip/hip_fp16.h>
#include <math.h>

#define D 128
#define D4 32   // float4s per fp32 row; also uint2s per fp16 row

// ---------------- CSR build ----------------

__global__ void count_kernel(const int* __restrict__ dst, int* __restrict__ counts, int E) {
    int e = blockIdx.x * 256 + threadIdx.x;
    if (e < E) atomicAdd(&counts[dst[e]], 1);
}

// per-256-chunk sums of counts; also dis[i] = rsqrt(deg) with deg = indeg+1 (self loop)
__global__ void block_sum_kernel(const int* __restrict__ counts, float* __restrict__ dis,
                                 int* __restrict__ bsums, int N) {
    __shared__ int sh[256];
    int t = threadIdx.x;
    int i = blockIdx.x * 256 + t;
    int v = (i < N) ? counts[i] : 0;
    if (i < N) dis[i] = rsqrtf((float)v + 1.0f);
    sh[t] = v;
    __syncthreads();
    for (int off = 128; off > 0; off >>= 1) {
        if (t < off) sh[t] += sh[t + off];
        __syncthreads();
    }
    if (t == 0) bsums[blockIdx.x] = sh[0];
}

// exclusive scan of NB (<=256) block sums, in place
__global__ void scan_bsums_kernel(int* __restrict__ bsums, int NB) {
    __shared__ int sh[256];
    int t = threadIdx.x;
    int v = (t < NB) ? bsums[t] : 0;
    sh[t] = v;
    __syncthreads();
    for (int off = 1; off < 256; off <<= 1) {
        int x = (t >= off) ? sh[t - off] : 0;
        __syncthreads();
        sh[t] += x;
        __syncthreads();
    }
    if (t < NB) bsums[t] = sh[t] - v;  // exclusive
}

__global__ void scan_scatter_kernel(const int* __restrict__ counts, const int* __restrict__ bsums,
                                    int* __restrict__ row_ptr, int N, int E) {
    __shared__ int sh[256];
    int t = threadIdx.x;
    int i = blockIdx.x * 256 + t;
    int v = (i < N) ? counts[i] : 0;
    sh[t] = v;
    __syncthreads();
    for (int off = 1; off < 256; off <<= 1) {
        int x = (t >= off) ? sh[t - off] : 0;
        __syncthreads();
        sh[t] += x;
        __syncthreads();
    }
    if (i < N) row_ptr[i] = bsums[blockIdx.x] + sh[t] - v;
    if (i == 0) row_ptr[N] = E;
}

__global__ void fill_csr_kernel(const int* __restrict__ src, const int* __restrict__ dst,
                                const int* __restrict__ row_ptr, int* __restrict__ fill,
                                int* __restrict__ col, int E) {
    int e = blockIdx.x * 256 + threadIdx.x;
    if (e < E) {
        int d = dst[e];
        int pos = atomicAdd(&fill[d], 1);
        col[row_ptr[d] + pos] = src[e];
    }
}

// ---------------- GEMM: C_fp16[N x 128] = dis[row] * (A[N x 128] @ W[128 x 128]) ------
// 32 rows per block, 256 threads = 8 row-groups x 32 col-groups, 4x4 register blocking.
// Epilogue pre-scales by dis[row] and narrows to fp16 (the aggregation gather table).

__global__ __launch_bounds__(256) void gemm_kernel(const float* __restrict__ A,
                                                   const float* __restrict__ W,
                                                   const float* __restrict__ dis,
                                                   __half* __restrict__ C, int N) {
    __shared__ float Wl[64 * D];   // 32KB: 64 k-rows of W
    __shared__ float4 Xs[32 * D4]; // 16KB: 32 rows x 128 floats

    int t = threadIdx.x;
    int row0 = blockIdx.x * 32;
    const float4* A4 = (const float4*)A;
    for (int i = t; i < 32 * D4; i += 256) {
        int r = row0 + (i >> 5);
        Xs[i] = (r < N) ? A4[(size_t)r * D4 + (i & 31)] : make_float4(0.f, 0.f, 0.f, 0.f);
    }

    int cg = t & 31;   // 4-col group: cols 4*cg..4*cg+3
    int rg = t >> 5;   // row group: local rows rg*4..rg*4+3
    float4 acc[4];
#pragma unroll
    for (int rr = 0; rr < 4; rr++) acc[rr] = make_float4(0.f, 0.f, 0.f, 0.f);

    const float4* W4 = (const float4*)W;
    float4* Wl4w = (float4*)Wl;
    const float4* Wl4 = (const float4*)Wl;

    for (int p = 0; p < 2; p++) {
        __syncthreads();
        for (int i = t; i < 2048; i += 256) Wl4w[i] = W4[p * 2048 + i];
        __syncthreads();
#pragma unroll 4
        for (int k4 = 0; k4 < 16; k4++) {
            float4 w0 = Wl4[(k4 * 4 + 0) * D4 + cg];
            float4 w1 = Wl4[(k4 * 4 + 1) * D4 + cg];
            float4 w2 = Wl4[(k4 * 4 + 2) * D4 + cg];
            float4 w3 = Wl4[(k4 * 4 + 3) * D4 + cg];
            int kg = p * 16 + k4;
#pragma unroll
            for (int rr = 0; rr < 4; rr++) {
                float4 xv = Xs[(rg * 4 + rr) * D4 + kg];
                acc[rr].x = fmaf(xv.x, w0.x, fmaf(xv.y, w1.x, fmaf(xv.z, w2.x, fmaf(xv.w, w3.x, acc[rr].x))));
                acc[rr].y = fmaf(xv.x, w0.y, fmaf(xv.y, w1.y, fmaf(xv.z, w2.y, fmaf(xv.w, w3.y, acc[rr].y))));
                acc[rr].z = fmaf(xv.x, w0.z, fmaf(xv.y, w1.z, fmaf(xv.z, w2.z, fmaf(xv.w, w3.z, acc[rr].z))));
                acc[rr].w = fmaf(xv.x, w0.w, fmaf(xv.y, w1.w, fmaf(xv.z, w2.w, fmaf(xv.w, w3.w, acc[rr].w))));
            }
        }
    }

    uint2* C2 = (uint2*)C;   // one uint2 = 4 halves; 32 per row
#pragma unroll
    for (int rr = 0; rr < 4; rr++) {
        int r = row0 + rg * 4 + rr;
        if (r < N) {
            float dr = dis[r];
            __half2 h0 = __floats2half2_rn(acc[rr].x * dr, acc[rr].y * dr);
            __half2 h1 = __floats2half2_rn(acc[rr].z * dr, acc[rr].w * dr);
            uint2 u;
            u.x = *(unsigned int*)&h0;
            u.y = *(unsigned int*)&h1;
            C2[(size_t)r * D4 + cg] = u;
        }
    }
}

// ---------------- Aggregation (pull, fp16 table, shfl-broadcast cols) ----------------
// hs is pre-scaled fp16: hs[s] = dis[s]*h[s].  out = relu(b + dis[i]*(sum hs[s] + hs[i]))
// 32 lanes per node (4 halves per lane), 8 nodes per 256-block.

__device__ __forceinline__ void acc_row(float4& acc, uint2 u) {
    __half2 p0 = *(__half2*)&u.x;
    __half2 p1 = *(__half2*)&u.y;
    float2 f0 = __half22float2(p0);
    float2 f1 = __half22float2(p1);
    acc.x += f0.x; acc.y += f0.y; acc.z += f1.x; acc.w += f1.y;
}

#define GATHER_BODY                                                         \
    float4 acc = make_float4(0.f, 0.f, 0.f, 0.f);                           \
    acc_row(acc, h2[(size_t)node * D4 + lane]); /* self term */             \
    int e0 = row_ptr[node], e1 = row_ptr[node + 1];                         \
    int deg = e1 - e0;                                                      \
    for (int base = 0; base < deg; base += 32) {                            \
        int cnt = min(32, deg - base);                                      \
        int myc = (base + lane < deg) ? col[e0 + base + lane] : 0;          \
        int j = 0;                                                          \
        for (; j + 8 <= cnt; j += 8) {                                      \
            int s0 = __shfl(myc, j + 0, 32); int s1 = __shfl(myc, j + 1, 32); \
            int s2 = __shfl(myc, j + 2, 32); int s3 = __shfl(myc, j + 3, 32); \
            int s4 = __shfl(myc, j + 4, 32); int s5 = __shfl(myc, j + 5, 32); \
            int s6 = __shfl(myc, j + 6, 32); int s7 = __shfl(myc, j + 7, 32); \
            uint2 u0 = h2[(size_t)s0 * D4 + lane];                          \
            uint2 u1 = h2[(size_t)s1 * D4 + lane];                          \
            uint2 u2 = h2[(size_t)s2 * D4 + lane];                          \
            uint2 u3 = h2[(size_t)s3 * D4 + lane];                          \
            uint2 u4 = h2[(size_t)s4 * D4 + lane];                          \
            uint2 u5 = h2[(size_t)s5 * D4 + lane];                          \
            uint2 u6 = h2[(size_t)s6 * D4 + lane];                          \
            uint2 u7 = h2[(size_t)s7 * D4 + lane];                          \
            acc_row(acc, u0); acc_row(acc, u1); acc_row(acc, u2); acc_row(acc, u3); \
            acc_row(acc, u4); acc_row(acc, u5); acc_row(acc, u6); acc_row(acc, u7); \
        }                                                                   \
        for (; j < cnt; j++) {                                              \
            int s = __shfl(myc, j, 32);                                     \
            acc_row(acc, h2[(size_t)s * D4 + lane]);                        \
        }                                                                   \
    }                                                                       \
    float di = dis[node];                                                   \
    float4 bb = ((const float4*)bias)[lane];                                \
    float4 o;                                                               \
    o.x = fmaxf(fmaf(di, acc.x, bb.x), 0.f);                                \
    o.y = fmaxf(fmaf(di, acc.y, bb.y), 0.f);                                \
    o.z = fmaxf(fmaf(di, acc.z, bb.z), 0.f);                                \
    o.w = fmaxf(fmaf(di, acc.w, bb.w), 0.f);

__global__ void agg_kernel(const __half* __restrict__ hs, const float* __restrict__ bias,
                           const int* __restrict__ row_ptr, const int* __restrict__ col,
                           const float* __restrict__ dis, float* __restrict__ out, int N) {
    int t = threadIdx.x;
    int node = blockIdx.x * 8 + (t >> 5);
    int lane = t & 31;
    if (node >= N) return;
    const uint2* h2 = (const uint2*)hs;
    GATHER_BODY
    ((float4*)out)[(size_t)node * D4 + lane] = o;
}

// Layer-2 aggregation with the sigmoid head fused: writes one score per node.
__global__ void agg_head_kernel(const __half* __restrict__ hs, const float* __restrict__ bias,
                                const int* __restrict__ row_ptr, const int* __restrict__ col,
                                const float* __restrict__ dis,
                                const float* __restrict__ head_w, const float* __restrict__ head_b,
                                float* __restrict__ out, int N) {
    int t = threadIdx.x;
    int node = blockIdx.x * 8 + (t >> 5);
    int lane = t & 31;
    if (node >= N) return;
    const uint2* h2 = (const uint2*)hs;
    GATHER_BODY
    float4 wv = ((const float4*)head_w)[lane];
    float s = o.x * wv.x + o.y * wv.y + o.z * wv.z + o.w * wv.w;
    for (int m = 1; m < 32; m <<= 1) s += __shfl_xor(s, m, 64);
    if (lane == 0) {
        float v = s + head_b[0];
        out[node] = 1.0f / (1.0f + expf(-v));
    }
}

// ---------------- launch ----------------

extern "C" void kernel_launch(void* const* d_in, const int* in_sizes, int n_in,
                              void* d_out, int out_size, void* d_ws, size_t ws_size,
                              hipStream_t stream) {
    const int*   edge   = (const int*)d_in[0];
    const float* emb    = (const float*)d_in[1];
    const float* W1     = (const float*)d_in[2];
    const float* b1     = (const float*)d_in[3];
    const float* W2     = (const float*)d_in[4];
    const float* b2     = (const float*)d_in[5];
    const float* head_w = (const float*)d_in[6];
    const float* head_b = (const float*)d_in[7];
    float* out = (float*)d_out;

    int E = in_sizes[0] / 2;
    int N = in_sizes[1] / D;
    const int* srcp = edge;
    const int* dstp = edge + E;

    char* w = (char*)d_ws;
    auto alloc = [&](size_t bytes) -> char* {
        char* p = w;
        w += (bytes + 15) & ~(size_t)15;
        return p;
    };
    __half* bufH   = (__half*)alloc((size_t)N * D * 2);  // 12.8 MB fp16 gather table
    float*  bufX   = (float*) alloc((size_t)N * D * 4);  // 25.6 MB fp32 x1
    int*   col     = (int*)   alloc((size_t)E * 4);      // 6.4 MB
    int*   counts  = (int*)   alloc((size_t)N * 4);
    int*   fill    = (int*)   alloc((size_t)N * 4);
    int*   row_ptr = (int*)   alloc((size_t)(N + 1) * 4);
    float* dis     = (float*) alloc((size_t)N * 4);
    int*   bsums   = (int*)   alloc(1024);

    int NB = (N + 255) / 256;       // 196 (<=256 required by scan_bsums)
    int gE = (E + 255) / 256;
    int gG = (N + 31) / 32;
    int gA = (N + 7) / 8;

    hipMemsetAsync(counts, 0, (size_t)N * 4, stream);
    hipMemsetAsync(fill,   0, (size_t)N * 4, stream);

    count_kernel<<<gE, 256, 0, stream>>>(dstp, counts, E);
    block_sum_kernel<<<NB, 256, 0, stream>>>(counts, dis, bsums, N);
    scan_bsums_kernel<<<1, 256, 0, stream>>>(bsums, NB);
    scan_scatter_kernel<<<NB, 256, 0, stream>>>(counts, bsums, row_ptr, N, E);
    fill_csr_kernel<<<gE, 256, 0, stream>>>(srcp, dstp, row_ptr, fill, col, E);

    gemm_kernel<<<gG, 256, 0, stream>>>(emb, W1, dis, bufH, N);                   // hs1 (fp16)
    agg_kernel<<<gA, 256, 0, stream>>>(bufH, b1, row_ptr, col, dis, bufX, N);     // x1 (fp32)
    gemm_kernel<<<gG, 256, 0, stream>>>(bufX, W2, dis, bufH, N);                  // hs2 (fp16)
    agg_head_kernel<<<gA, 256, 0, stream>>>(bufH, b2, row_ptr, col, dis,
                                            head_w, head_b, out, N);              // scores
}